// Round 10
// baseline (433.024 us; speedup 1.0000x reference)
//
#include <hip/hip_runtime.h>

typedef float f32x4 __attribute__((ext_vector_type(4)));
typedef unsigned int u32x2 __attribute__((ext_vector_type(2)));
typedef __bf16 bf16x2 __attribute__((ext_vector_type(2)));
typedef __bf16 bf16x8 __attribute__((ext_vector_type(8)));

static_assert(sizeof(bf16x8) == 16, "bf16x8 must be 16B");

#define NB 4096
#define NT 64
#define NBLK 256
#define BTF (NB * NT * 64)   // 16777216

// Barrier draining ONLY lgkmcnt (LDS); global loads/stores stay in flight.
#define LGKM_BAR() do { \
    asm volatile("s_waitcnt lgkmcnt(0)" ::: "memory"); \
    __builtin_amdgcn_s_barrier(); \
  } while (0)

__device__ __forceinline__ unsigned short f2bf(float x) {
  return __builtin_bit_cast(unsigned short, (__bf16)x);
}
__device__ __forceinline__ unsigned int pk2(float lo, float hi) {
  bf16x2 t; t[0] = (__bf16)lo; t[1] = (__bf16)hi;
  return __builtin_bit_cast(unsigned int, t);
}
__device__ __forceinline__ float bf2f(unsigned int us) {   // low 16 bits -> f32
  return __builtin_bit_cast(float, us << 16);
}

__device__ __forceinline__ f32x4 mfma16(bf16x8 a, bf16x8 b, f32x4 c) {
  return __builtin_amdgcn_mfma_f32_16x16x32_bf16(a, b, c, 0, 0, 0);
}

__device__ __forceinline__ bf16x8 cvt8(f32x4 a, f32x4 b) {
  bf16x8 r;
#pragma unroll
  for (int j = 0; j < 4; ++j) { r[j] = (__bf16)a[j]; r[4 + j] = (__bf16)b[j]; }
  return r;
}

__device__ __forceinline__ bf16x8 loadW8(const float* __restrict__ row, int k0) {
  f32x4 a = *(const f32x4*)(row + k0);
  f32x4 b = *(const f32x4*)(row + k0 + 4);
  return cvt8(a, b);
}

__device__ __forceinline__ bf16x8 loadW8zd(const float* __restrict__ row, int k0, int col) {
  f32x4 a = *(const f32x4*)(row + k0);
  f32x4 b = *(const f32x4*)(row + k0 + 4);
  bf16x8 r;
#pragma unroll
  for (int j = 0; j < 4; ++j) {
    r[j]     = (k0 + j     == col) ? (__bf16)0.f : (__bf16)a[j];
    r[4 + j] = (k0 + 4 + j == col) ? (__bf16)0.f : (__bf16)b[j];
  }
  return r;
}

__device__ __forceinline__ float sigm(float x) { return 1.f / (1.f + __expf(-x)); }
__device__ __forceinline__ float tanh_fast(float x) { return 1.f - 2.f / (__expf(2.f * x) + 1.f); }

__global__ __launch_bounds__(512, 2) void rits_main_kernel(
    const float* __restrict__ values, const float* __restrict__ masks,
    const float* __restrict__ deltas,
    const float* __restrict__ W_dh, const float* __restrict__ b_dh,
    const float* __restrict__ W_dx, const float* __restrict__ b_dx,
    const float* __restrict__ W_hist, const float* __restrict__ b_hist,
    const float* __restrict__ W_feat, const float* __restrict__ b_feat,
    const float* __restrict__ W_comb, const float* __restrict__ b_comb,
    const float* __restrict__ W_ih, const float* __restrict__ b_ih,
    const float* __restrict__ W_hh, const float* __restrict__ b_hh,
    float* __restrict__ out_imp, float* __restrict__ out_est,
    float* __restrict__ out_h, float* __restrict__ loss_ws) {
  const int tid = threadIdx.x;
  const int w = tid >> 6;          // wave 0..7 (0-3 "low", 4-7 "high")
  const int l = tid & 63;          // lane
  const int rA = l & 15;           // MFMA A-row / C-col index
  const int kg = l >> 4;           // k-group 0..3
  const int wg = blockIdx.x;
  const int b0 = wg * 16;
  const int colh = w * 16 + rA;          // 0..127
  const int colw = (w & 3) * 16 + rA;    // 0..63
  const int s = tid & 255;               // staging/loss index
  const int sr = s >> 4, sq = s & 15;    // 16 rows x 16 quads

  __shared__ float sX[2][16][68];                            // x f32 (exact)
  __shared__ unsigned short sMb[2][16][72], sDb[2][16][72];  // m, d bf16
  __shared__ unsigned short sHb[2][16][136];                 // decayed h~
  __shared__ unsigned short sWh[64][136];                    // W_hist bf16 [col][k]
  __shared__ unsigned short sXc4[4][16][72];                 // per-low-wave x_c bounce
  __shared__ unsigned short sCcb[16][72];                    // c_c bf16
  __shared__ unsigned short sXhb[16][72], sZhb[16][72];      // xh, zh bf16 (loss)
  __shared__ float sAlT[64][20];                             // alpha transposed [col][row]
  __shared__ float sCh[16][68], sCc[16][68];                 // f32 outputs
  __shared__ float sWdxB[128];                               // diag(W_dx) | b_dx
  __shared__ float sLoss[4][4];

  // ---------------- one-time init ----------------
  if (tid < 64)       sWdxB[tid] = W_dx[tid * 65];
  else if (tid < 128) sWdxB[tid] = b_dx[tid - 64];
#pragma unroll
  for (int i = 0; i < 4; ++i) sHb[0][kg * 4 + i][colh] = 0;   // h~(0) = 0
  {
    // W_hist -> LDS bf16, [col][k] layout (B-fragment readable)
    int c = tid >> 3, k0 = (tid & 7) * 16;
    const float* wr = W_hist + (size_t)c * 128 + k0;
    *(bf16x8*)&sWh[c][k0]     = loadW8(wr, 0);
    *(bf16x8*)&sWh[c][k0 + 8] = loadW8(wr, 8);
  }

  // ---------------- weights -> registers ----------------
  bf16x8 wgf[4][8];
#pragma unroll
  for (int g = 0; g < 4; ++g) {
    int col = g * 128 + colh;
#pragma unroll
    for (int kk = 0; kk < 4; ++kk) wgf[g][kk] = loadW8(W_ih + (size_t)col * 128, kk * 32 + kg * 8);
#pragma unroll
    for (int kk = 0; kk < 4; ++kk) wgf[g][4 + kk] = loadW8(W_hh + (size_t)col * 128, kk * 32 + kg * 8);
  }
  bf16x8 wdhf[2];
#pragma unroll
  for (int kk = 0; kk < 2; ++kk) wdhf[kk] = loadW8(W_dh + (size_t)colh * 64, kk * 32 + kg * 8);

  // low: W_feat (own cols, zero diag); high: W_comb (own cols)
  bf16x8 wfeat[2], wcomb[4];
  if (w < 4) {
#pragma unroll
    for (int kk = 0; kk < 2; ++kk) wfeat[kk] = loadW8zd(W_feat + (size_t)colw * 64, kk * 32 + kg * 8, colw);
#pragma unroll
    for (int kk = 0; kk < 4; ++kk) { bf16x8 z = {}; wcomb[kk] = z; }
  } else {
#pragma unroll
    for (int kk = 0; kk < 4; ++kk) wcomb[kk] = loadW8(W_comb + (size_t)colw * 128, kk * 32 + kg * 8);
#pragma unroll
    for (int kk = 0; kk < 2; ++kk) { bf16x8 z = {}; wfeat[kk] = z; }
  }

  const float bdh = b_dh[colh];
  float bhist4[4];
  float bfeat = 0.f, bcomb = 0.f;
  if (w < 4) {
#pragma unroll
    for (int jt = 0; jt < 4; ++jt) bhist4[jt] = b_hist[jt * 16 + rA];
    bfeat = b_feat[colw];
  } else {
#pragma unroll
    for (int jt = 0; jt < 4; ++jt) bhist4[jt] = 0.f;
    bcomb = b_comb[colw];
  }
  float bg[4];
#pragma unroll
  for (int g = 0; g < 4; ++g) bg[g] = b_ih[g * 128 + colh] + b_hh[g * 128 + colh];

  f32x4 h_reg = {0.f, 0.f, 0.f, 0.f};
  f32x4 c_reg = {0.f, 0.f, 0.f, 0.f};

  // hoisted global bases
  const size_t gbase = (size_t)(b0 + sr) * 4096 + sq * 4;     // staging (w>=4)
  const int orow = (tid & 255) >> 4, oq = tid & 15;
  float* pout = ((tid < 256) ? out_est : out_imp) + (size_t)(b0 + orow) * 4096 + oq * 4;
  const float* sOut0 = (tid < 256) ? &sCh[orow][oq * 4] : &sCc[orow][oq * 4];

  // ---------------- prologue ----------------
  if (w >= 4) {
    f32x4 vx0 = *(const f32x4*)&values[gbase];
    f32x4 vm0 = *(const f32x4*)&masks[gbase];
    f32x4 vd0 = *(const f32x4*)&deltas[gbase];
    *(f32x4*)&sX[0][sr][sq * 4] = vx0;
    u32x2 pm, pd;
    pm[0] = pk2(vm0[0], vm0[1]); pm[1] = pk2(vm0[2], vm0[3]);
    pd[0] = pk2(vd0[0], vd0[1]); pd[1] = pk2(vd0[2], vd0[3]);
    *(u32x2*)&sMb[0][sr][sq * 4] = pm;
    *(u32x2*)&sDb[0][sr][sq * 4] = pd;
  }
  LGKM_BAR();

  // alpha(0) (high waves) + issue t=1 loads
  f32x4 vx, vm, vd;
  if (w >= 4) {
    vx = *(const f32x4*)&values[gbase + 64];
    vm = *(const f32x4*)&masks[gbase + 64];
    vd = *(const f32x4*)&deltas[gbase + 64];
    bf16x8 d0 = *(const bf16x8*)&sDb[0][rA][kg * 8];
    bf16x8 d1 = *(const bf16x8*)&sDb[0][rA][32 + kg * 8];
    bf16x8 gx0, gx1;
#pragma unroll
    for (int j = 0; j < 8; ++j) {
      int k0 = kg * 8 + j, k1 = 32 + kg * 8 + j;
      gx0[j] = (__bf16)__expf(-fmaxf((float)d0[j] * sWdxB[k0] + sWdxB[64 + k0], 0.f));
      gx1[j] = (__bf16)__expf(-fmaxf((float)d1[j] * sWdxB[k1] + sWdxB[64 + k1], 0.f));
    }
    f32x4 aal = {0.f, 0.f, 0.f, 0.f};
    aal = mfma16(gx0, wcomb[0], aal);
    aal = mfma16(gx1, wcomb[1], aal);
    bf16x8 m0f = *(const bf16x8*)&sMb[0][rA][kg * 8];
    bf16x8 m1f = *(const bf16x8*)&sMb[0][rA][32 + kg * 8];
    aal = mfma16(m0f, wcomb[2], aal);
    aal = mfma16(m1f, wcomb[3], aal);
    f32x4 alv;
#pragma unroll
    for (int i = 0; i < 4; ++i) alv[i] = sigm(aal[i] + bcomb);
    *(f32x4*)&sAlT[colw][kg * 4] = alv;
  }
  LGKM_BAR();

  // ---------------- time loop: 2 lgkm-only barriers per step ----------------
  for (int t = 0; t < NT; ++t) {
    const int p = t & 1;

    // ========== PHASE A ==========
    if (t > 0 && tid < 4) {
      float lsv = sLoss[0][tid] + sLoss[1][tid] + sLoss[2][tid] + sLoss[3][tid];
      loss_ws[((size_t)(t - 1) * NBLK + wg) * 4 + tid] = lsv;
    }
    if (w < 4) {
      // full-width x_h GEMM: A = h~ frags, B = W_hist from LDS
      bf16x8 haf[4];
#pragma unroll
      for (int kk = 0; kk < 4; ++kk) haf[kk] = *(const bf16x8*)&sHb[p][rA][kk * 32 + kg * 8];
      float xh_w[4], xr_w[4], mr_w[4];
#pragma unroll
      for (int jt = 0; jt < 4; ++jt) {
        f32x4 a = {0.f, 0.f, 0.f, 0.f};
#pragma unroll
        for (int kk = 0; kk < 4; ++kk) {
          bf16x8 bw = *(const bf16x8*)&sWh[jt * 16 + rA][kk * 32 + kg * 8];
          a = mfma16(haf[kk], bw, a);
        }
        int col = jt * 16 + rA;
#pragma unroll
        for (int i = 0; i < 4; ++i) {
          int row = kg * 4 + i;
          float xh = a[i] + bhist4[jt];
          float xr = sX[p][row][col];
          float mr = bf2f(sMb[p][row][col]);
          float xc = mr * xr + (1.f - mr) * xh;
          sXc4[w][row][col] = f2bf(xc);
          if (jt == w) { xh_w[i] = xh; xr_w[i] = xr; mr_w[i] = mr; }
        }
      }
#pragma unroll
      for (int i = 0; i < 4; ++i) sXhb[kg * 4 + i][colw] = f2bf(xh_w[i]);
      // in-wave bounce: read x_c A-frags (compiler inserts lgkmcnt wait)
      bf16x8 xa0 = *(const bf16x8*)&sXc4[w][rA][kg * 8];
      bf16x8 xa1 = *(const bf16x8*)&sXc4[w][rA][32 + kg * 8];
      f32x4 az = {0.f, 0.f, 0.f, 0.f};
      az = mfma16(xa0, wfeat[0], az);
      az = mfma16(xa1, wfeat[1], az);
      f32x4 alv = *(const f32x4*)&sAlT[colw][kg * 4];
#pragma unroll
      for (int i = 0; i < 4; ++i) {
        int row = kg * 4 + i;
        float zh = az[i] + bfeat;
        float al = alv[i];
        float ch = al * zh + (1.f - al) * xh_w[i];
        float cc = mr_w[i] * xr_w[i] + (1.f - mr_w[i]) * ch;
        sCh[row][colw] = ch;
        sCc[row][colw] = cc;
        sCcb[row][colw] = f2bf(cc);
        sZhb[row][colw] = f2bf(zh);
      }
    } else {
      // staging writes of t+1 (loads issued last phase B / prologue)
      *(f32x4*)&sX[p ^ 1][sr][sq * 4] = vx;
      u32x2 pm, pd;
      pm[0] = pk2(vm[0], vm[1]); pm[1] = pk2(vm[2], vm[3]);
      pd[0] = pk2(vd[0], vd[1]); pd[1] = pk2(vd[2], vd[3]);
      *(u32x2*)&sMb[p ^ 1][sr][sq * 4] = pm;
      *(u32x2*)&sDb[p ^ 1][sr][sq * 4] = pd;
    }
    LGKM_BAR();   // bar 1: sCcb/sCh/sCc/sXhb/sZhb + staged t+1 ready

    // ========== PHASE B ==========
    // issue t+2 loads (consumed in next phase A)
    if (w >= 4) {
      int tq = (t + 2 <= NT - 1) ? t + 2 : NT - 1;
      size_t ga = gbase + (size_t)(tq << 6);
      vx = *(const f32x4*)&values[ga];
      vm = *(const f32x4*)&masks[ga];
      vd = *(const f32x4*)&deltas[ga];
    }
    // est/imp coalesced stores
    *(f32x4*)pout = *(const f32x4*)sOut0;
    pout += 64;
    // gate GEMM (32 MFMA) + LSTM
    {
      f32x4 acc[4];
#pragma unroll
      for (int g = 0; g < 4; ++g) { f32x4 z = {0.f, 0.f, 0.f, 0.f}; acc[g] = z; }
#pragma unroll
      for (int kk = 0; kk < 8; ++kk) {
        bf16x8 a;
        if (kk < 2)      a = *(const bf16x8*)&sCcb[rA][kk * 32 + kg * 8];
        else if (kk < 4) a = *(const bf16x8*)&sMb[p][rA][(kk - 2) * 32 + kg * 8];
        else             a = *(const bf16x8*)&sHb[p][rA][(kk - 4) * 32 + kg * 8];
#pragma unroll
        for (int g = 0; g < 4; ++g) acc[g] = mfma16(a, wgf[g][kk], acc[g]);
      }
#pragma unroll
      for (int i = 0; i < 4; ++i) {
        float ii = sigm(acc[0][i] + bg[0]);
        float ff = sigm(acc[1][i] + bg[1]);
        float g_ = tanh_fast(acc[2][i] + bg[2]);
        float oo = sigm(acc[3][i] + bg[3]);
        float c_ = ff * c_reg[i] + ii * g_;
        c_reg[i] = c_;
        h_reg[i] = oo * tanh_fast(c_);
      }
    }
    if (t < NT - 1) {
      // gamma_h(t+1); decay h -> sHb[p^1]
      bf16x8 a0 = *(const bf16x8*)&sDb[p ^ 1][rA][kg * 8];
      bf16x8 a1 = *(const bf16x8*)&sDb[p ^ 1][rA][32 + kg * 8];
      f32x4 ga4 = {0.f, 0.f, 0.f, 0.f};
      ga4 = mfma16(a0, wdhf[0], ga4);
      ga4 = mfma16(a1, wdhf[1], ga4);
#pragma unroll
      for (int i = 0; i < 4; ++i) {
        float g = __expf(-fmaxf(ga4[i] + bdh, 0.f));
        h_reg[i] *= g;
        sHb[p ^ 1][kg * 4 + i][colh] = f2bf(h_reg[i]);
      }
      // high: gamma_x(t+1) in-reg (from same d frags) + alpha(t+1) GEMM -> sAlT
      if (w >= 4) {
        bf16x8 gx0, gx1;
#pragma unroll
        for (int j = 0; j < 8; ++j) {
          int k0 = kg * 8 + j, k1 = 32 + kg * 8 + j;
          gx0[j] = (__bf16)__expf(-fmaxf((float)a0[j] * sWdxB[k0] + sWdxB[64 + k0], 0.f));
          gx1[j] = (__bf16)__expf(-fmaxf((float)a1[j] * sWdxB[k1] + sWdxB[64 + k1], 0.f));
        }
        f32x4 aal = {0.f, 0.f, 0.f, 0.f};
        aal = mfma16(gx0, wcomb[0], aal);
        aal = mfma16(gx1, wcomb[1], aal);
        bf16x8 m0f = *(const bf16x8*)&sMb[p ^ 1][rA][kg * 8];
        bf16x8 m1f = *(const bf16x8*)&sMb[p ^ 1][rA][32 + kg * 8];
        aal = mfma16(m0f, wcomb[2], aal);
        aal = mfma16(m1f, wcomb[3], aal);
        f32x4 alv;
#pragma unroll
        for (int i = 0; i < 4; ++i) alv[i] = sigm(aal[i] + bcomb);
        *(f32x4*)&sAlT[colw][kg * 4] = alv;
      }
    } else {
#pragma unroll
      for (int i = 0; i < 4; ++i) out_h[(size_t)(b0 + kg * 4 + i) * 128 + colh] = h_reg[i];
    }
    // high waves: loss for step t (from LDS, bf16 xh/zh)
    if (w >= 4) {
      int lr = sr, lc0 = sq * 4;
      f32x4 xv = *(const f32x4*)&sX[p][lr][lc0];
      f32x4 chv = *(const f32x4*)&sCh[lr][lc0];
      float n1 = 0.f, n2 = 0.f, n3 = 0.f, den = 0.f;
#pragma unroll
      for (int j = 0; j < 4; ++j) {
        float m = bf2f(sMb[p][lr][lc0 + j]);
        float x = xv[j];
        float xh = bf2f(sXhb[lr][lc0 + j]);
        float zh = bf2f(sZhb[lr][lc0 + j]);
        n1 += fabsf(xh - x) * m;
        n2 += fabsf(zh - x) * m;
        n3 += fabsf(chv[j] - x) * m;
        den += m;
      }
#pragma unroll
      for (int off = 32; off > 0; off >>= 1) {
        n1 += __shfl_down(n1, off);
        n2 += __shfl_down(n2, off);
        n3 += __shfl_down(n3, off);
        den += __shfl_down(den, off);
      }
      if (l == 0) {
        f32x4 lv; lv[0] = n1; lv[1] = n2; lv[2] = n3; lv[3] = den;
        *(f32x4*)&sLoss[w - 4][0] = lv;
      }
    }
    LGKM_BAR();   // bar 2: sHb[p^1], sAlT, sLoss ready; step-t LDS reads done
  }

  // final loss_ws writeback for t = NT-1
  if (tid < 4) {
    float lsv = sLoss[0][tid] + sLoss[1][tid] + sLoss[2][tid] + sLoss[3][tid];
    loss_ws[((size_t)(NT - 1) * NBLK + wg) * 4 + tid] = lsv;
  }
}

__global__ void rits_loss_kernel(const float* __restrict__ ws, float* __restrict__ out_loss) {
  int tid = threadIdx.x;  // 64 threads; thread t handles step t
  float n1 = 0.f, n2 = 0.f, n3 = 0.f, den = 0.f;
  for (int g = 0; g < NBLK; ++g) {
    const float* p = &ws[((size_t)tid * NBLK + g) * 4];
    n1 += p[0]; n2 += p[1]; n3 += p[2]; den += p[3];
  }
  float lt = (n1 + n2 + n3) / (den + 1e-12f);
#pragma unroll
  for (int off = 32; off > 0; off >>= 1) lt += __shfl_down(lt, off);
  if (tid == 0) out_loss[0] = lt / 192.f;   // / (T * 3)
}

extern "C" void kernel_launch(void* const* d_in, const int* in_sizes, int n_in,
                              void* d_out, int out_size, void* d_ws, size_t ws_size,
                              hipStream_t stream) {
  const float* values = (const float*)d_in[0];
  const float* masks  = (const float*)d_in[1];
  const float* deltas = (const float*)d_in[2];
  const float* W_dh   = (const float*)d_in[3];
  const float* b_dh   = (const float*)d_in[4];
  const float* W_dx   = (const float*)d_in[5];
  const float* b_dx   = (const float*)d_in[6];
  const float* W_hist = (const float*)d_in[7];
  const float* b_hist = (const float*)d_in[8];
  const float* W_feat = (const float*)d_in[9];
  const float* b_feat = (const float*)d_in[10];
  const float* W_comb = (const float*)d_in[11];
  const float* b_comb = (const float*)d_in[12];
  const float* W_ih   = (const float*)d_in[13];
  const float* b_ih   = (const float*)d_in[14];
  const float* W_hh   = (const float*)d_in[15];
  const float* b_hh   = (const float*)d_in[16];

  float* out = (float*)d_out;
  float* out_imp = out;                       // [B,T,F]
  float* out_est = out + (size_t)BTF;         // [B,T,F]
  float* out_h   = out + (size_t)2 * BTF;     // [B,H]
  float* out_ls  = out + (size_t)2 * BTF + (size_t)NB * 128;  // scalar
  float* loss_ws = (float*)d_ws;              // [T][NBLK][4]

  rits_main_kernel<<<NBLK, 512, 0, stream>>>(
      values, masks, deltas, W_dh, b_dh, W_dx, b_dx, W_hist, b_hist,
      W_feat, b_feat, W_comb, b_comb, W_ih, b_ih, W_hh, b_hh,
      out_imp, out_est, out_h, loss_ws);
  rits_loss_kernel<<<1, 64, 0, stream>>>(loss_ws, out_ls);
}